// Round 3
// baseline (785.025 us; speedup 1.0000x reference)
//
#include <hip/hip_runtime.h>
#include <hip/hip_bf16.h>

#define NN 50000
#define EE 800000

typedef __attribute__((ext_vector_type(8))) short short8v;
typedef __attribute__((ext_vector_type(4))) float f32x4;

__device__ __forceinline__ float bf2f(unsigned short u) {
    return __uint_as_float(((unsigned int)u) << 16);
}
__device__ __forceinline__ unsigned short f2bf(float f) {
    unsigned int u = __float_as_uint(f);
    unsigned int r = 0x7FFF + ((u >> 16) & 1);
    return (unsigned short)((u + r) >> 16);
}

// ---------------- fp32 -> bf16 conversion (vectorized) ----------------
__global__ void cvt_f2bf(const float* __restrict__ in, unsigned short* __restrict__ out, int n4) {
    int i = blockIdx.x * 256 + threadIdx.x;
    if (i >= n4) return;
    float4 v = reinterpret_cast<const float4*>(in)[i];
    ushort4 o;
    o.x = f2bf(v.x); o.y = f2bf(v.y); o.z = f2bf(v.z); o.w = f2bf(v.w);
    reinterpret_cast<ushort4*>(out)[i] = o;
}

// ---------------- CSR construction ----------------
__global__ void count_k(const int* __restrict__ dst, int* __restrict__ cursor) {
    int i = blockIdx.x * 256 + threadIdx.x;
    if (i >= 2 * EE) return;
    int r = (i >= EE) ? 1 : 0;
    atomicAdd(&cursor[r * NN + dst[i]], 1);
}

__global__ __launch_bounds__(1024) void scan_k(int* __restrict__ cursor, int* __restrict__ rowptr) {
    int r = blockIdx.x;
    int* cnt = cursor + r * NN;          // counts in, exclusive prefix out
    int* rp  = rowptr + r * (NN + 1);
    int tid = threadIdx.x;
    const int CH = (NN + 1023) / 1024;   // 49
    int beg = tid * CH;
    int end = beg + CH; if (end > NN) end = NN;
    int s = 0;
    for (int i = beg; i < end && i < NN; ++i) s += cnt[i];
    __shared__ int sums[1024];
    sums[tid] = s;
    __syncthreads();
    for (int offd = 1; offd < 1024; offd <<= 1) {
        int v = 0;
        if (tid >= offd) v = sums[tid - offd];
        __syncthreads();
        sums[tid] += v;
        __syncthreads();
    }
    int run = sums[tid] - s;             // exclusive offset for this chunk
    for (int i = beg; i < end && i < NN; ++i) {
        int c = cnt[i];
        rp[i] = run;
        cnt[i] = run;                    // cursor for scatter
        run += c;
    }
    if (tid == 1023) rp[NN] = sums[1023];
}

__global__ void scatter_k(const int* __restrict__ src, const int* __restrict__ dst,
                          int* __restrict__ cursor, int* __restrict__ csr) {
    int i = blockIdx.x * 256 + threadIdx.x;
    if (i >= 2 * EE) return;
    int r = (i >= EE) ? 1 : 0;
    int pos = atomicAdd(&cursor[r * NN + dst[i]], 1);
    csr[r * EE + pos] = src[i];
}

// ---------------- MFMA GEMM: C[n,o] = sum_k A[n,k]*W[o,k]; A,W bf16; K=256 ----------------
template<bool BF16OUT>
__global__ __launch_bounds__(256) void gemm_mfma(
    const unsigned short* __restrict__ A,   // [M][256] bf16
    const unsigned short* __restrict__ W,   // per-rel [256][256] bf16
    void* __restrict__ Cout, int relW, long relC, int M)
{
    __shared__ unsigned short sA[128][72];  // 64-k chunk, stride 72 (2-way bank alias = free)
    __shared__ unsigned short sB[128][72];
    const int K = 256;
    int tid = threadIdx.x;
    int wid = tid >> 6, lane = tid & 63;
    int wr = wid >> 1, wc = wid & 1;
    int n0 = blockIdx.x * 128;
    int o0 = blockIdx.y * 128;
    const unsigned short* Wr = W + (size_t)blockIdx.z * relW;

    f32x4 acc[4][4] = {};

    for (int k0 = 0; k0 < K; k0 += 64) {
        #pragma unroll
        for (int p = 0; p < 4; ++p) {
            int flat = p * 256 + tid;            // 0..1023
            int row = flat >> 3, k8 = (flat & 7) * 8;
            int gr = n0 + row;
            short8v va = {0, 0, 0, 0, 0, 0, 0, 0};
            if (gr < M) va = *reinterpret_cast<const short8v*>(A + (size_t)gr * K + k0 + k8);
            *reinterpret_cast<short8v*>(&sA[row][k8]) = va;
            short8v vb = *reinterpret_cast<const short8v*>(Wr + (size_t)(o0 + row) * K + k0 + k8);
            *reinterpret_cast<short8v*>(&sB[row][k8]) = vb;
        }
        __syncthreads();
        #pragma unroll
        for (int kk = 0; kk < 2; ++kk) {
            short8v af[4], bf[4];
            int klo = kk * 32 + (lane >> 4) * 8;
            #pragma unroll
            for (int m = 0; m < 4; ++m)
                af[m] = *reinterpret_cast<const short8v*>(&sA[wr * 64 + m * 16 + (lane & 15)][klo]);
            #pragma unroll
            for (int n = 0; n < 4; ++n)
                bf[n] = *reinterpret_cast<const short8v*>(&sB[wc * 64 + n * 16 + (lane & 15)][klo]);
            #pragma unroll
            for (int m = 0; m < 4; ++m)
                #pragma unroll
                for (int n = 0; n < 4; ++n)
                    acc[m][n] = __builtin_amdgcn_mfma_f32_16x16x32_bf16(af[m], bf[n], acc[m][n], 0, 0, 0);
        }
        __syncthreads();
    }
    int col0 = o0 + wc * 64;
    int rbase = (lane >> 4) * 4;
    #pragma unroll
    for (int m = 0; m < 4; ++m) {
        #pragma unroll
        for (int j = 0; j < 4; ++j) {
            int gr = n0 + wr * 64 + m * 16 + rbase + j;
            if (gr >= M) continue;
            #pragma unroll
            for (int n = 0; n < 4; ++n) {
                int gc = col0 + n * 16 + (lane & 15);
                size_t idx = (size_t)blockIdx.z * relC + (size_t)gr * 256 + gc;
                if constexpr (BF16OUT) ((unsigned short*)Cout)[idx] = f2bf(acc[m][n][j]);
                else                   ((float*)Cout)[idx] = acc[m][n][j];
            }
        }
    }
}

// ---------------- Layer-1 edge softmax + aggregation (H=4, D=64) ----------------
// Direct exp (no running max): scores are O(few sigma), exp cannot overflow fp32.
// 4 nodes per 256-thread block, one wave per node.
__global__ __launch_bounds__(256) void agg1_k(
    const unsigned short* __restrict__ feat,   // [2][NN][256] bf16
    const float* __restrict__ x,               // [NN][256]
    const float* __restrict__ a1,              // [2][256]
    const float* __restrict__ b1,              // [2][256]
    const int* __restrict__ rowptr, const int* __restrict__ csr,
    unsigned short* __restrict__ hb)           // [NN][256] bf16 out
{
    int wid = threadIdx.x >> 6, lane = threadIdx.x & 63;
    int n = blockIdx.x * 4 + wid;
    if (n >= NN) return;
    int c = lane * 4;
    float t0 = 0.f, t1 = 0.f, t2 = 0.f, t3 = 0.f;
    #pragma unroll
    for (int r = 0; r < 2; ++r) {
        const unsigned short* fr = feat + (size_t)r * NN * 256;
        ushort4 ud = *reinterpret_cast<const ushort4*>(fr + (size_t)n * 256 + c);
        float fd0 = bf2f(ud.x), fd1 = bf2f(ud.y), fd2 = bf2f(ud.z), fd3 = bf2f(ud.w);
        float4 av = *reinterpret_cast<const float4*>(a1 + r * 256 + c);
        // leaky(t) = 0.6t + 0.4|t|; fold attn coeff in
        float p60 = 0.6f * av.x, q40 = 0.4f * av.x;
        float p61 = 0.6f * av.y, q41 = 0.4f * av.y;
        float p62 = 0.6f * av.z, q42 = 0.4f * av.z;
        float p63 = 0.6f * av.w, q43 = 0.4f * av.w;
        float lsum = 0.f;
        float a0 = 0.f, a1v = 0.f, a2v = 0.f, a3 = 0.f;
        int beg = rowptr[r * (NN + 1) + n], end = rowptr[r * (NN + 1) + n + 1];
        for (int e = beg; e < end; ++e) {
            int s = csr[r * EE + e];
            ushort4 us = *reinterpret_cast<const ushort4*>(fr + (size_t)s * 256 + c);
            float fs0 = bf2f(us.x), fs1 = bf2f(us.y), fs2 = bf2f(us.z), fs3 = bf2f(us.w);
            float t, part;
            t = fs0 + fd0; part  = p60 * t + q40 * fabsf(t);
            t = fs1 + fd1; part += p61 * t; part += q41 * fabsf(t);
            t = fs2 + fd2; part += p62 * t; part += q42 * fabsf(t);
            t = fs3 + fd3; part += p63 * t; part += q43 * fabsf(t);
            part += __shfl_xor(part, 1);
            part += __shfl_xor(part, 2);
            part += __shfl_xor(part, 4);
            part += __shfl_xor(part, 8);
            float p = __expf(part);
            lsum += p;
            a0  += p * fs0;
            a1v += p * fs1;
            a2v += p * fs2;
            a3  += p * fs3;
        }
        float inv = 1.f / fmaxf(lsum, 1e-16f);
        t0 += a0 * inv; t1 += a1v * inv; t2 += a2v * inv; t3 += a3 * inv;
    }
    size_t o = (size_t)n * 256 + c;
    float4 xv = *reinterpret_cast<const float4*>(x + o);
    float v0 = fmaxf(t0 + 2.f * xv.x + b1[c + 0] + b1[256 + c + 0], 0.f);
    float v1 = fmaxf(t1 + 2.f * xv.y + b1[c + 1] + b1[256 + c + 1], 0.f);
    float v2 = fmaxf(t2 + 2.f * xv.z + b1[c + 2] + b1[256 + c + 2], 0.f);
    float v3 = fmaxf(t3 + 2.f * xv.w + b1[c + 3] + b1[256 + c + 3], 0.f);
    ushort4 ho;
    ho.x = f2bf(v0); ho.y = f2bf(v1); ho.z = f2bf(v2); ho.w = f2bf(v3);
    reinterpret_cast<ushort4*>(hb)[(size_t)n * 64 + lane] = ho;
}

// ---------------- Layer-2 helpers ----------------
__global__ void build_wcat_bf(const float* __restrict__ W2, const float* __restrict__ Wres2,
                              unsigned short* __restrict__ Wcat) {
    int i = blockIdx.x * 256 + threadIdx.x;
    if (i >= 256 * 256) return;
    int o = i >> 8, k = i & 255;
    int sel = o >> 6, row = o & 63;
    int r = sel >> 1;
    const float* Wsrc = (sel & 1) ? Wres2 : W2;
    Wcat[i] = f2bf(Wsrc[((size_t)r * 64 + row) * 256 + k]);
}

__global__ void post2(const float* __restrict__ G, const float* __restrict__ b2,
                      unsigned short* __restrict__ feat2, float* __restrict__ base) {
    int i = blockIdx.x * 256 + threadIdx.x;
    if (i >= NN * 64) return;
    int n = i >> 6, d = i & 63;
    const float* g = G + (size_t)n * 256;
    feat2[i] = f2bf(g[d]);
    feat2[(size_t)NN * 64 + i] = f2bf(g[128 + d]);
    base[i] = g[64 + d] + g[192 + d] + b2[d] + b2[64 + d];
}

// ---------------- Layer-2 edge softmax + aggregation (H=1, D=64) ----------------
__global__ __launch_bounds__(256) void agg2_k(
    const unsigned short* __restrict__ feat2,  // [2][NN][64] bf16
    const float* __restrict__ base,
    const float* __restrict__ a2,              // [2][64]
    const int* __restrict__ rowptr, const int* __restrict__ csr,
    float* __restrict__ out)
{
    int wid = threadIdx.x >> 6, lane = threadIdx.x & 63;
    int n = blockIdx.x * 4 + wid;
    if (n >= NN) return;
    float tot = 0.f;
    #pragma unroll
    for (int r = 0; r < 2; ++r) {
        const unsigned short* fr = feat2 + (size_t)r * NN * 64;
        float fd = bf2f(fr[(size_t)n * 64 + lane]);
        float av = a2[r * 64 + lane];
        float p6 = 0.6f * av, q4 = 0.4f * av;
        float lsum = 0.f, acc = 0.f;
        int beg = rowptr[r * (NN + 1) + n], end = rowptr[r * (NN + 1) + n + 1];
        for (int e = beg; e < end; ++e) {
            int s = csr[r * EE + e];
            float fs = bf2f(fr[(size_t)s * 64 + lane]);
            float t = fs + fd;
            float part = p6 * t + q4 * fabsf(t);
            part += __shfl_xor(part, 1);
            part += __shfl_xor(part, 2);
            part += __shfl_xor(part, 4);
            part += __shfl_xor(part, 8);
            part += __shfl_xor(part, 16);
            part += __shfl_xor(part, 32);
            float p = __expf(part);
            lsum += p;
            acc += p * fs;
        }
        tot += acc / fmaxf(lsum, 1e-16f);
    }
    size_t o = (size_t)n * 64 + lane;
    out[o] = fmaxf(tot + base[o], 0.f);
}

extern "C" void kernel_launch(void* const* d_in, const int* in_sizes, int n_in,
                              void* d_out, int out_size, void* d_ws, size_t ws_size,
                              hipStream_t stream) {
    (void)in_sizes; (void)n_in; (void)out_size; (void)ws_size;
    const float* x     = (const float*)d_in[0];
    const int*   src   = (const int*)d_in[1];
    const int*   dst   = (const int*)d_in[2];
    const float* W1    = (const float*)d_in[3];
    const float* a1    = (const float*)d_in[4];
    const float* b1    = (const float*)d_in[5];
    const float* W2    = (const float*)d_in[6];
    const float* a2    = (const float*)d_in[7];
    const float* b2    = (const float*)d_in[8];
    const float* Wres2 = (const float*)d_in[9];
    float* out = (float*)d_out;

    char* w = (char*)d_ws;
    size_t off = 0;
    auto alloc = [&](size_t bytes) -> void* {
        void* p = w + off;
        off = (off + bytes + 255) & ~(size_t)255;
        return p;
    };
    int* cursor = (int*)alloc((size_t)2 * NN * sizeof(int));
    int* rowptr = (int*)alloc((size_t)2 * (NN + 1) * sizeof(int));
    int* csr    = (int*)alloc((size_t)2 * EE * sizeof(int));
    unsigned short* feat1 = (unsigned short*)alloc((size_t)2 * NN * 256 * 2); // aliased as G (fp32 NN*256)
    float* G = (float*)feat1;
    unsigned short* xb = (unsigned short*)alloc((size_t)NN * 256 * 2);
    unsigned short* hb = (unsigned short*)alloc((size_t)NN * 256 * 2);
    unsigned short* W1b = (unsigned short*)alloc((size_t)2 * 256 * 256 * 2);
    unsigned short* Wcatb = (unsigned short*)alloc((size_t)256 * 256 * 2);
    unsigned short* feat2 = (unsigned short*)alloc((size_t)2 * NN * 64 * 2);
    float* base = (float*)alloc((size_t)NN * 64 * 4);

    // conversions
    cvt_f2bf<<<(NN * 256 / 4 + 255) / 256, 256, 0, stream>>>(x, xb, NN * 256 / 4);
    cvt_f2bf<<<(2 * 256 * 256 / 4 + 255) / 256, 256, 0, stream>>>(W1, W1b, 2 * 256 * 256 / 4);
    build_wcat_bf<<<(256 * 256 + 255) / 256, 256, 0, stream>>>(W2, Wres2, Wcatb);

    // CSR
    hipMemsetAsync(cursor, 0, (size_t)2 * NN * sizeof(int), stream);
    count_k<<<(2 * EE + 255) / 256, 256, 0, stream>>>(dst, cursor);
    scan_k<<<2, 1024, 0, stream>>>(cursor, rowptr);
    scatter_k<<<(2 * EE + 255) / 256, 256, 0, stream>>>(src, dst, cursor, csr);

    // Layer 1
    dim3 g1((NN + 127) / 128, 2, 2);
    gemm_mfma<true><<<g1, 256, 0, stream>>>(xb, W1b, feat1, 256 * 256, (long)NN * 256, NN);
    agg1_k<<<(NN + 3) / 4, 256, 0, stream>>>(feat1, x, a1, b1, rowptr, csr, hb);

    // Layer 2
    dim3 g2((NN + 127) / 128, 2, 1);
    gemm_mfma<false><<<g2, 256, 0, stream>>>(hb, Wcatb, G, 0, 0, NN);
    post2<<<(NN * 64 + 255) / 256, 256, 0, stream>>>(G, b2, feat2, base);
    agg2_k<<<(NN + 3) / 4, 256, 0, stream>>>(feat2, base, a2, rowptr, csr, out);
}

// Round 4
// 665.069 us; speedup vs baseline: 1.1804x; 1.1804x over previous
//
#include <hip/hip_runtime.h>
#include <hip/hip_bf16.h>

#define NN 50000
#define EE 800000

typedef __attribute__((ext_vector_type(8))) short short8v;
typedef __attribute__((ext_vector_type(4))) float f32x4;

__device__ __forceinline__ float bf2f(unsigned short u) {
    return __uint_as_float(((unsigned int)u) << 16);
}
__device__ __forceinline__ unsigned short f2bf(float f) {
    unsigned int u = __float_as_uint(f);
    unsigned int r = 0x7FFF + ((u >> 16) & 1);
    return (unsigned short)((u + r) >> 16);
}

// ---------------- fp32 -> bf16 conversion (vectorized) ----------------
__global__ void cvt_f2bf(const float* __restrict__ in, unsigned short* __restrict__ out, int n4) {
    int i = blockIdx.x * 256 + threadIdx.x;
    if (i >= n4) return;
    float4 v = reinterpret_cast<const float4*>(in)[i];
    ushort4 o;
    o.x = f2bf(v.x); o.y = f2bf(v.y); o.z = f2bf(v.z); o.w = f2bf(v.w);
    reinterpret_cast<ushort4*>(out)[i] = o;
}

// ---------------- CSR construction ----------------
__global__ void count_k(const int* __restrict__ dst, int* __restrict__ cursor) {
    int i = blockIdx.x * 256 + threadIdx.x;
    if (i >= 2 * EE) return;
    int r = (i >= EE) ? 1 : 0;
    atomicAdd(&cursor[r * NN + dst[i]], 1);
}

__global__ __launch_bounds__(1024) void scan_k(int* __restrict__ cursor, int* __restrict__ rowptr) {
    int r = blockIdx.x;
    int* cnt = cursor + r * NN;          // counts in, exclusive prefix out
    int* rp  = rowptr + r * (NN + 1);
    int tid = threadIdx.x;
    const int CH = (NN + 1023) / 1024;   // 49
    int beg = tid * CH;
    int end = beg + CH; if (end > NN) end = NN;
    int s = 0;
    for (int i = beg; i < end && i < NN; ++i) s += cnt[i];
    __shared__ int sums[1024];
    sums[tid] = s;
    __syncthreads();
    for (int offd = 1; offd < 1024; offd <<= 1) {
        int v = 0;
        if (tid >= offd) v = sums[tid - offd];
        __syncthreads();
        sums[tid] += v;
        __syncthreads();
    }
    int run = sums[tid] - s;             // exclusive offset for this chunk
    for (int i = beg; i < end && i < NN; ++i) {
        int c = cnt[i];
        rp[i] = run;
        cnt[i] = run;                    // cursor for scatter
        run += c;
    }
    if (tid == 1023) rp[NN] = sums[1023];
}

__global__ void scatter_k(const int* __restrict__ src, const int* __restrict__ dst,
                          int* __restrict__ cursor, int* __restrict__ csr) {
    int i = blockIdx.x * 256 + threadIdx.x;
    if (i >= 2 * EE) return;
    int r = (i >= EE) ? 1 : 0;
    int pos = atomicAdd(&cursor[r * NN + dst[i]], 1);
    csr[r * EE + pos] = src[i];
}

// ---------------- MFMA GEMM: C[n,o] = sum_k A[n,k]*W[o,k]; A,W bf16; K=256 ----------------
template<bool BF16OUT>
__global__ __launch_bounds__(256) void gemm_mfma(
    const unsigned short* __restrict__ A,   // [M][256] bf16
    const unsigned short* __restrict__ W,   // per-rel [256][256] bf16
    void* __restrict__ Cout, int relW, long relC, int M)
{
    __shared__ unsigned short sA[128][72];  // 64-k chunk, stride 72 (2-way bank alias = free)
    __shared__ unsigned short sB[128][72];
    const int K = 256;
    int tid = threadIdx.x;
    int wid = tid >> 6, lane = tid & 63;
    int wr = wid >> 1, wc = wid & 1;
    int n0 = blockIdx.x * 128;
    int o0 = blockIdx.y * 128;
    const unsigned short* Wr = W + (size_t)blockIdx.z * relW;

    f32x4 acc[4][4] = {};

    for (int k0 = 0; k0 < K; k0 += 64) {
        #pragma unroll
        for (int p = 0; p < 4; ++p) {
            int flat = p * 256 + tid;            // 0..1023
            int row = flat >> 3, k8 = (flat & 7) * 8;
            int gr = n0 + row;
            short8v va = {0, 0, 0, 0, 0, 0, 0, 0};
            if (gr < M) va = *reinterpret_cast<const short8v*>(A + (size_t)gr * K + k0 + k8);
            *reinterpret_cast<short8v*>(&sA[row][k8]) = va;
            short8v vb = *reinterpret_cast<const short8v*>(Wr + (size_t)(o0 + row) * K + k0 + k8);
            *reinterpret_cast<short8v*>(&sB[row][k8]) = vb;
        }
        __syncthreads();
        #pragma unroll
        for (int kk = 0; kk < 2; ++kk) {
            short8v af[4], bf[4];
            int klo = kk * 32 + (lane >> 4) * 8;
            #pragma unroll
            for (int m = 0; m < 4; ++m)
                af[m] = *reinterpret_cast<const short8v*>(&sA[wr * 64 + m * 16 + (lane & 15)][klo]);
            #pragma unroll
            for (int n = 0; n < 4; ++n)
                bf[n] = *reinterpret_cast<const short8v*>(&sB[wc * 64 + n * 16 + (lane & 15)][klo]);
            #pragma unroll
            for (int m = 0; m < 4; ++m)
                #pragma unroll
                for (int n = 0; n < 4; ++n)
                    acc[m][n] = __builtin_amdgcn_mfma_f32_16x16x32_bf16(af[m], bf[n], acc[m][n], 0, 0, 0);
        }
        __syncthreads();
    }
    int col0 = o0 + wc * 64;
    int rbase = (lane >> 4) * 4;
    #pragma unroll
    for (int m = 0; m < 4; ++m) {
        #pragma unroll
        for (int j = 0; j < 4; ++j) {
            int gr = n0 + wr * 64 + m * 16 + rbase + j;
            if (gr >= M) continue;
            #pragma unroll
            for (int n = 0; n < 4; ++n) {
                int gc = col0 + n * 16 + (lane & 15);
                size_t idx = (size_t)blockIdx.z * relC + (size_t)gr * 256 + gc;
                if constexpr (BF16OUT) ((unsigned short*)Cout)[idx] = f2bf(acc[m][n][j]);
                else                   ((float*)Cout)[idx] = acc[m][n][j];
            }
        }
    }
}

// ---------------- Layer-1 edge softmax + aggregation (H=4, D=64) ----------------
// One 64-thread workgroup per node (fine-grained retirement beats wave packing: R3 lesson).
// Direct exp, no running max: |score| is O(1), exp cannot overflow fp32.
__global__ __launch_bounds__(64) void agg1_k(
    const unsigned short* __restrict__ feat,   // [2][NN][256] bf16
    const unsigned short* __restrict__ xb,     // [NN][256] bf16 (residual)
    const float* __restrict__ a1,              // [2][256]
    const float* __restrict__ b1,              // [2][256]
    const int* __restrict__ rowptr, const int* __restrict__ csr,
    unsigned short* __restrict__ hb)           // [NN][256] bf16 out
{
    int n = blockIdx.x, lane = threadIdx.x;
    int c = lane * 4;
    float t0 = 0.f, t1 = 0.f, t2 = 0.f, t3 = 0.f;
    #pragma unroll
    for (int r = 0; r < 2; ++r) {
        const unsigned short* fr = feat + (size_t)r * NN * 256;
        ushort4 ud = *reinterpret_cast<const ushort4*>(fr + (size_t)n * 256 + c);
        float fd0 = bf2f(ud.x), fd1 = bf2f(ud.y), fd2 = bf2f(ud.z), fd3 = bf2f(ud.w);
        float4 av = *reinterpret_cast<const float4*>(a1 + r * 256 + c);
        // leaky(t)*a = (0.6a)t + (0.4a)|t|
        float p60 = 0.6f * av.x, q40 = 0.4f * av.x;
        float p61 = 0.6f * av.y, q41 = 0.4f * av.y;
        float p62 = 0.6f * av.z, q42 = 0.4f * av.z;
        float p63 = 0.6f * av.w, q43 = 0.4f * av.w;
        float lsum = 0.f;
        float a0 = 0.f, a1v = 0.f, a2v = 0.f, a3 = 0.f;
        int beg = rowptr[r * (NN + 1) + n], end = rowptr[r * (NN + 1) + n + 1];
        for (int e = beg; e < end; ++e) {
            int s = csr[r * EE + e];
            ushort4 us = *reinterpret_cast<const ushort4*>(fr + (size_t)s * 256 + c);
            float fs0 = bf2f(us.x), fs1 = bf2f(us.y), fs2 = bf2f(us.z), fs3 = bf2f(us.w);
            float t, part;
            t = fs0 + fd0; part  = p60 * t + q40 * fabsf(t);
            t = fs1 + fd1; part += p61 * t; part += q41 * fabsf(t);
            t = fs2 + fd2; part += p62 * t; part += q42 * fabsf(t);
            t = fs3 + fd3; part += p63 * t; part += q43 * fabsf(t);
            part += __shfl_xor(part, 1);
            part += __shfl_xor(part, 2);
            part += __shfl_xor(part, 4);
            part += __shfl_xor(part, 8);
            float p = __expf(part);
            lsum += p;
            a0  += p * fs0;
            a1v += p * fs1;
            a2v += p * fs2;
            a3  += p * fs3;
        }
        float inv = 1.f / fmaxf(lsum, 1e-16f);
        t0 += a0 * inv; t1 += a1v * inv; t2 += a2v * inv; t3 += a3 * inv;
    }
    size_t o = (size_t)n * 256 + c;
    ushort4 xv4 = *reinterpret_cast<const ushort4*>(xb + o);
    float v0 = fmaxf(t0 + 2.f * bf2f(xv4.x) + b1[c + 0] + b1[256 + c + 0], 0.f);
    float v1 = fmaxf(t1 + 2.f * bf2f(xv4.y) + b1[c + 1] + b1[256 + c + 1], 0.f);
    float v2 = fmaxf(t2 + 2.f * bf2f(xv4.z) + b1[c + 2] + b1[256 + c + 2], 0.f);
    float v3 = fmaxf(t3 + 2.f * bf2f(xv4.w) + b1[c + 3] + b1[256 + c + 3], 0.f);
    ushort4 ho;
    ho.x = f2bf(v0); ho.y = f2bf(v1); ho.z = f2bf(v2); ho.w = f2bf(v3);
    reinterpret_cast<ushort4*>(hb)[(size_t)n * 64 + lane] = ho;
}

// ---------------- Layer-2 helpers ----------------
__global__ void build_wcat_bf(const float* __restrict__ W2, const float* __restrict__ Wres2,
                              unsigned short* __restrict__ Wcat) {
    int i = blockIdx.x * 256 + threadIdx.x;
    if (i >= 256 * 256) return;
    int o = i >> 8, k = i & 255;
    int sel = o >> 6, row = o & 63;
    int r = sel >> 1;
    const float* Wsrc = (sel & 1) ? Wres2 : W2;
    Wcat[i] = f2bf(Wsrc[((size_t)r * 64 + row) * 256 + k]);
}

__global__ void post2(const float* __restrict__ G, const float* __restrict__ b2,
                      unsigned short* __restrict__ feat2, float* __restrict__ base) {
    int i = blockIdx.x * 256 + threadIdx.x;
    if (i >= NN * 64) return;
    int n = i >> 6, d = i & 63;
    const float* g = G + (size_t)n * 256;
    feat2[i] = f2bf(g[d]);
    feat2[(size_t)NN * 64 + i] = f2bf(g[128 + d]);
    base[i] = g[64 + d] + g[192 + d] + b2[d] + b2[64 + d];
}

// ---------------- Layer-2 edge softmax + aggregation (H=1, D=64) ----------------
__global__ __launch_bounds__(64) void agg2_k(
    const unsigned short* __restrict__ feat2,  // [2][NN][64] bf16
    const float* __restrict__ base,
    const float* __restrict__ a2,              // [2][64]
    const int* __restrict__ rowptr, const int* __restrict__ csr,
    float* __restrict__ out)
{
    int n = blockIdx.x, lane = threadIdx.x;
    float tot = 0.f;
    #pragma unroll
    for (int r = 0; r < 2; ++r) {
        const unsigned short* fr = feat2 + (size_t)r * NN * 64;
        float fd = bf2f(fr[(size_t)n * 64 + lane]);
        float av = a2[r * 64 + lane];
        float p6 = 0.6f * av, q4 = 0.4f * av;
        float lsum = 0.f, acc = 0.f;
        int beg = rowptr[r * (NN + 1) + n], end = rowptr[r * (NN + 1) + n + 1];
        for (int e = beg; e < end; ++e) {
            int s = csr[r * EE + e];
            float fs = bf2f(fr[(size_t)s * 64 + lane]);
            float t = fs + fd;
            float part = p6 * t + q4 * fabsf(t);
            part += __shfl_xor(part, 1);
            part += __shfl_xor(part, 2);
            part += __shfl_xor(part, 4);
            part += __shfl_xor(part, 8);
            part += __shfl_xor(part, 16);
            part += __shfl_xor(part, 32);
            float p = __expf(part);
            lsum += p;
            acc += p * fs;
        }
        tot += acc / fmaxf(lsum, 1e-16f);
    }
    size_t o = (size_t)n * 64 + lane;
    out[o] = fmaxf(tot + base[o], 0.f);
}

extern "C" void kernel_launch(void* const* d_in, const int* in_sizes, int n_in,
                              void* d_out, int out_size, void* d_ws, size_t ws_size,
                              hipStream_t stream) {
    (void)in_sizes; (void)n_in; (void)out_size; (void)ws_size;
    const float* x     = (const float*)d_in[0];
    const int*   src   = (const int*)d_in[1];
    const int*   dst   = (const int*)d_in[2];
    const float* W1    = (const float*)d_in[3];
    const float* a1    = (const float*)d_in[4];
    const float* b1    = (const float*)d_in[5];
    const float* W2    = (const float*)d_in[6];
    const float* a2    = (const float*)d_in[7];
    const float* b2    = (const float*)d_in[8];
    const float* Wres2 = (const float*)d_in[9];
    float* out = (float*)d_out;

    char* w = (char*)d_ws;
    size_t off = 0;
    auto alloc = [&](size_t bytes) -> void* {
        void* p = w + off;
        off = (off + bytes + 255) & ~(size_t)255;
        return p;
    };
    int* cursor = (int*)alloc((size_t)2 * NN * sizeof(int));
    int* rowptr = (int*)alloc((size_t)2 * (NN + 1) * sizeof(int));
    int* csr    = (int*)alloc((size_t)2 * EE * sizeof(int));
    unsigned short* feat1 = (unsigned short*)alloc((size_t)2 * NN * 256 * 2); // aliased as G (fp32 NN*256)
    float* G = (float*)feat1;
    unsigned short* xb = (unsigned short*)alloc((size_t)NN * 256 * 2);
    unsigned short* hb = (unsigned short*)alloc((size_t)NN * 256 * 2);
    unsigned short* W1b = (unsigned short*)alloc((size_t)2 * 256 * 256 * 2);
    unsigned short* Wcatb = (unsigned short*)alloc((size_t)256 * 256 * 2);
    unsigned short* feat2 = (unsigned short*)alloc((size_t)2 * NN * 64 * 2);
    float* base = (float*)alloc((size_t)NN * 64 * 4);

    // conversions
    cvt_f2bf<<<(NN * 256 / 4 + 255) / 256, 256, 0, stream>>>(x, xb, NN * 256 / 4);
    cvt_f2bf<<<(2 * 256 * 256 / 4 + 255) / 256, 256, 0, stream>>>(W1, W1b, 2 * 256 * 256 / 4);
    build_wcat_bf<<<(256 * 256 + 255) / 256, 256, 0, stream>>>(W2, Wres2, Wcatb);

    // CSR
    hipMemsetAsync(cursor, 0, (size_t)2 * NN * sizeof(int), stream);
    count_k<<<(2 * EE + 255) / 256, 256, 0, stream>>>(dst, cursor);
    scan_k<<<2, 1024, 0, stream>>>(cursor, rowptr);
    scatter_k<<<(2 * EE + 255) / 256, 256, 0, stream>>>(src, dst, cursor, csr);

    // Layer 1
    dim3 g1((NN + 127) / 128, 2, 2);
    gemm_mfma<true><<<g1, 256, 0, stream>>>(xb, W1b, feat1, 256 * 256, (long)NN * 256, NN);
    agg1_k<<<NN, 64, 0, stream>>>(feat1, xb, a1, b1, rowptr, csr, hb);

    // Layer 2
    dim3 g2((NN + 127) / 128, 2, 1);
    gemm_mfma<false><<<g2, 256, 0, stream>>>(hb, Wcatb, G, 0, 0, NN);
    post2<<<(NN * 64 + 255) / 256, 256, 0, stream>>>(G, b2, feat2, base);
    agg2_k<<<NN, 64, 0, stream>>>(feat2, base, a2, rowptr, csr, out);
}